// Round 5
// baseline (1848.904 us; speedup 1.0000x reference)
//
#include <hip/hip_runtime.h>
#include <math.h>

typedef float  f32x4  __attribute__((ext_vector_type(4)));
typedef __bf16 bf16x8 __attribute__((ext_vector_type(8)));
typedef __bf16 bf16x4 __attribute__((ext_vector_type(4)));

// Swin block: B=32, H=W=56, C=384, WS=7, SHIFT=3, NH=12, HD=32
constexpr int Cc    = 384;
constexpr int Nh    = 12;
constexpr int Nt    = 49;
constexpr int Bw    = 2048;
constexpr int Mrows = 100352;           // B*H*W
constexpr int CHW   = 512;              // windows per chunk
constexpr int CHR   = CHW * Nt;         // 25088 rows per chunk (= Mrows/4)
constexpr size_t TQ = (size_t)CHW * Nh * Nt * 32;  // elems per q/k/v plane

// async global->LDS, 16B per lane; dest = wave-uniform base + lane*16
__device__ __forceinline__ void gload16(void* lds, const void* g) {
  __builtin_amdgcn_global_load_lds(
      (const __attribute__((address_space(1))) unsigned int*)(uintptr_t)g,
      (__attribute__((address_space(3))) unsigned int*)(uintptr_t)lds,
      16, 0, 0);
}

// ---------------------------------------------------------------------------
// Weight convert: W[K][N] fp32 -> Wt[N][K] bf16 (transposed, GEMM B input)
// ---------------------------------------------------------------------------
__global__ __launch_bounds__(256) void wconv_k(
    const float* __restrict__ W, __bf16* __restrict__ Wt, int K, int N)
{
  __shared__ float T[32][36];
  const int k0 = blockIdx.y * 32, n0 = blockIdx.x * 32;
  const int t = threadIdx.x;
  {
    int r = t >> 3, c = (t & 7) * 4;
    float4 v = *(const float4*)&W[(size_t)(k0 + r) * N + n0 + c];
    T[r][c] = v.x; T[r][c + 1] = v.y; T[r][c + 2] = v.z; T[r][c + 3] = v.w;
  }
  __syncthreads();
  int n = t >> 3, k4 = (t & 7) * 4;
  bf16x4 o;
  o[0] = (__bf16)T[k4 + 0][n];
  o[1] = (__bf16)T[k4 + 1][n];
  o[2] = (__bf16)T[k4 + 2][n];
  o[3] = (__bf16)T[k4 + 3][n];
  *(bf16x4*)&Wt[(size_t)(n0 + n) * K + k0 + k4] = o;
}

// ---------------------------------------------------------------------------
// LN1 + cyclic shift(-3,-3) + window partition -> xwb bf16 [Mrows][384]
// One wave per output window-row.
// ---------------------------------------------------------------------------
__global__ __launch_bounds__(256) void ln1_gather_k(
    const float* __restrict__ x, const float* __restrict__ g,
    const float* __restrict__ bt, __bf16* __restrict__ xw)
{
  int row  = blockIdx.x * 4 + threadIdx.y;
  int lane = threadIdx.x;
  int w  = row / 49, nn = row - w * 49;
  int b  = w >> 6, wi = (w & 63) >> 3, wj = w & 7;
  int ii = nn / 7, jj = nn - ii * 7;
  int y  = (wi * 7 + ii + 3) % 56;
  int xx = (wj * 7 + jj + 3) % 56;
  const float* xr = x + ((size_t)b * 3136 + y * 56 + xx) * Cc;
  float vals[6], s = 0.f, s2 = 0.f;
#pragma unroll
  for (int t = 0; t < 6; ++t) {
    float v = xr[lane + t * 64];
    vals[t] = v; s += v; s2 += v * v;
  }
#pragma unroll
  for (int off = 32; off > 0; off >>= 1) {
    s  += __shfl_xor(s, off, 64);
    s2 += __shfl_xor(s2, off, 64);
  }
  float mean = s * (1.f / 384.f);
  float var  = s2 * (1.f / 384.f) - mean * mean;
  float rstd = rsqrtf(var + 1e-5f);
  __bf16* orow = xw + (size_t)row * Cc;
#pragma unroll
  for (int t = 0; t < 6; ++t) {
    int c = lane + t * 64;
    orow[c] = (__bf16)((vals[t] - mean) * rstd * g[c] + bt[c]);
  }
}

// ---------------------------------------------------------------------------
// LN2 apply: h fp32 [Mrows][384] -> hb bf16 (no gather)
// ---------------------------------------------------------------------------
__global__ __launch_bounds__(256) void ln_apply_k(
    const float* __restrict__ h, const float* __restrict__ g,
    const float* __restrict__ bt, __bf16* __restrict__ o)
{
  int row  = blockIdx.x * 4 + threadIdx.y;
  int lane = threadIdx.x;
  const float* xr = h + (size_t)row * Cc;
  float vals[6], s = 0.f, s2 = 0.f;
#pragma unroll
  for (int t = 0; t < 6; ++t) {
    float v = xr[lane + t * 64];
    vals[t] = v; s += v; s2 += v * v;
  }
#pragma unroll
  for (int off = 32; off > 0; off >>= 1) {
    s  += __shfl_xor(s, off, 64);
    s2 += __shfl_xor(s2, off, 64);
  }
  float mean = s * (1.f / 384.f);
  float var  = s2 * (1.f / 384.f) - mean * mean;
  float rstd = rsqrtf(var + 1e-5f);
  __bf16* orow = o + (size_t)row * Cc;
#pragma unroll
  for (int t = 0; t < 6; ++t) {
    int c = lane + t * 64;
    orow[c] = (__bf16)((vals[t] - mean) * rstd * g[c] + bt[c]);
  }
}

// ---------------------------------------------------------------------------
// bf16 MFMA GEMM: C = A[M,K] @ Bt[N,K]^T (+bias). 128x128 tile, BK=32,
// 4 waves, 4x4 16x16x32 frags/wave, global_load_lds staging (m97 structure).
// MODE 0 qkv : out bf16 scatter -> qkvc[3][CHW][Nh][49][32]     (local rows)
// MODE 1 proj: out fp32 d_out, window-reverse scatter, + x      (global rows)
// MODE 2 fc1 : out bf16 m1c, GELU                               (local rows)
// MODE 3 fc2 : out fp32 d_out rows p0+row, +=                   (p0 offset)
// ---------------------------------------------------------------------------
template<int MODE, int K, int NOUT>
__global__ __launch_bounds__(256) void gemm_k(
    const __bf16* __restrict__ A, const __bf16* __restrict__ Bt,
    const float* __restrict__ bias, void* __restrict__ outv,
    const float* __restrict__ e0, int p0)
{
  __shared__ __bf16 Alds[128][32];
  __shared__ __bf16 Blds[128][32];
  const int tid  = threadIdx.x;
  const int lane = tid & 63, w = tid >> 6;
  const int m0 = blockIdx.y * 128, n0 = blockIdx.x * 128;
  const int wr = (w >> 1) * 64, wc = (w & 1) * 64;

  f32x4 acc[4][4] = {};

  // staging: wave w owns rows [w*32, w*32+32) of each tile; lane*16B dest
  const int sr = lane >> 2;              // slab row 0..15
  const int sc = (lane & 3) * 8;         // k-elem offset (16B)
  const __bf16* ag = A  + (size_t)(m0 + w * 32 + sr) * K + sc;
  const __bf16* bg = Bt + (size_t)(n0 + w * 32 + sr) * K + sc;
  __bf16* al = &Alds[w * 32][0];
  __bf16* bl = &Blds[w * 32][0];

  const int fr = lane & 15;              // fragment row/col
  const int fk = (lane >> 4) * 8;        // fragment k offset

  for (int k0 = 0; k0 < K; k0 += 32) {
    __syncthreads();                     // prev compute done before overwrite
    gload16(al,           ag + k0);
    gload16(al + 16 * 32, ag + (size_t)16 * K + k0);
    gload16(bl,           bg + k0);
    gload16(bl + 16 * 32, bg + (size_t)16 * K + k0);
    __syncthreads();                     // vmcnt(0) drain + barrier

    bf16x8 af[4], bf[4];
#pragma unroll
    for (int mi = 0; mi < 4; ++mi)
      af[mi] = *(const bf16x8*)&Alds[wr + mi * 16 + fr][fk];
#pragma unroll
    for (int ni = 0; ni < 4; ++ni)
      bf[ni] = *(const bf16x8*)&Blds[wc + ni * 16 + fr][fk];
#pragma unroll
    for (int mi = 0; mi < 4; ++mi)
#pragma unroll
      for (int ni = 0; ni < 4; ++ni)
        acc[mi][ni] = __builtin_amdgcn_mfma_f32_16x16x32_bf16(
            af[mi], bf[ni], acc[mi][ni], 0, 0, 0);
  }

  // epilogue: D col = lane&15, row = (lane>>4)*4 + reg
  const int col_l = lane & 15;
  const int row_l = (lane >> 4) * 4;
#pragma unroll
  for (int mi = 0; mi < 4; ++mi) {
#pragma unroll
    for (int ni = 0; ni < 4; ++ni) {
#pragma unroll
      for (int r = 0; r < 4; ++r) {
        int row  = m0 + wr + mi * 16 + row_l + r;
        int ccol = n0 + wc + ni * 16 + col_l;
        float val = acc[mi][ni][r] + bias[ccol];
        if (MODE == 0) {
          __bf16* out = (__bf16*)outv;
          int t = ccol / 384, rem = ccol - t * 384;
          int hh = rem >> 5, dd = rem & 31;
          int wl = row / 49, nn = row - wl * 49;
          out[(((size_t)t * CHW + wl) * Nh + hh) * (Nt * 32) + nn * 32 + dd] =
              (__bf16)val;
        } else if (MODE == 1) {
          float* out = (float*)outv;
          int wg = row / 49, nn = row - wg * 49;
          int b = wg >> 6, wi = (wg & 63) >> 3, wj = wg & 7;
          int ii = nn / 7, jj = nn - ii * 7;
          int y  = (wi * 7 + ii + 3) % 56;
          int xx = (wj * 7 + jj + 3) % 56;
          size_t dest = ((size_t)b * 3136 + y * 56 + xx) * Cc + ccol;
          out[dest] = e0[dest] + val;     // e0 = x (shortcut); h
        } else if (MODE == 2) {
          __bf16* out = (__bf16*)outv;
          float ge = 0.5f * val * (1.0f + erff(val * 0.7071067811865476f));
          out[(size_t)row * NOUT + ccol] = (__bf16)ge;
        } else {
          float* out = (float*)outv;
          size_t idx = (size_t)(p0 + row) * NOUT + ccol;
          out[idx] += val;                // out holds h; final = h + mlp
        }
      }
    }
  }
}

// ---------------------------------------------------------------------------
// Windowed attention (fp32 internal, bf16 i/o), block per (local window, head)
// ---------------------------------------------------------------------------
__global__ __launch_bounds__(256) void attn_k(
    const __bf16* __restrict__ qkv, const float* __restrict__ table,
    const int* __restrict__ ridx, __bf16* __restrict__ out, int w0)
{
  __shared__ float qs[Nt * 32], ks[Nt * 32], vs[Nt * 32], Ss[Nt * Nt];
  int wl = blockIdx.x / 12, hh = blockIdx.x - wl * 12;
  int tid = threadIdx.x;
  size_t base = ((size_t)wl * Nh + hh) * (Nt * 32);
  const __bf16* qp = qkv + base;
  const __bf16* kp = qkv + TQ + base;
  const __bf16* vp = qkv + 2 * TQ + base;
  constexpr float scale = 0.17677669529663687f;   // 1/sqrt(32)
  for (int e = tid; e < Nt * 32; e += 256) {
    qs[e] = (float)qp[e] * scale;
    ks[e] = (float)kp[e];
    vs[e] = (float)vp[e];
  }
  __syncthreads();
  for (int e = tid; e < Nt * Nt; e += 256) {
    int n = e / 49, m = e - n * 49;
    const float* qn = qs + n * 32;
    const float* km = ks + m * 32;
    float a = 0.f;
#pragma unroll
    for (int d = 0; d < 32; ++d) a += qn[d] * km[d];
    Ss[e] = a + table[ridx[e] * 12 + hh];
  }
  __syncthreads();
  if (tid < 49) {
    float* row = Ss + tid * 49;
    float mx = -1e30f;
    for (int m = 0; m < 49; ++m) mx = fmaxf(mx, row[m]);
    float sum = 0.f;
    for (int m = 0; m < 49; ++m) { float p = expf(row[m] - mx); row[m] = p; sum += p; }
    float inv = 1.f / sum;
    for (int m = 0; m < 49; ++m) row[m] *= inv;
  }
  __syncthreads();
  int gw = w0 + wl;
  for (int e = tid; e < Nt * 32; e += 256) {
    int n = e >> 5, d = e & 31;
    const float* sr = Ss + n * 49;
    float a = 0.f;
#pragma unroll
    for (int m = 0; m < 49; ++m) a += sr[m] * vs[m * 32 + d];
    out[((size_t)gw * 49 + n) * Cc + hh * 32 + d] = (__bf16)a;
  }
}

// ---------------------------------------------------------------------------
// Workspace layout (peak ~220 MiB):
//   @0      wq bf16 [1152][384]   (0.85MB)
//   @1MiB   wp bf16 [384][384]
//   @2MiB   w1 bf16 [1536][384]
//   @4MiB   w2 bf16 [384][1536]
//   @6MiB   xwb bf16 [Mrows][384] (73.5MiB) -> overlaid by hb after qkv phase
//   @90MiB  qkvc bf16 chunk (55.1MiB)       -> dead after attn
//   @146MiB obuf bf16 [Mrows][384] (73.5MiB)-> overlaid by m1c after proj
// ---------------------------------------------------------------------------
extern "C" void kernel_launch(void* const* d_in, const int* in_sizes, int n_in,
                              void* d_out, int out_size, void* d_ws, size_t ws_size,
                              hipStream_t stream)
{
  const float* x      = (const float*)d_in[0];
  const float* n1g    = (const float*)d_in[1];
  const float* n1b    = (const float*)d_in[2];
  const float* qkv_w  = (const float*)d_in[3];
  const float* qkv_b  = (const float*)d_in[4];
  const float* proj_w = (const float*)d_in[5];
  const float* proj_b = (const float*)d_in[6];
  const float* rtab   = (const float*)d_in[7];
  const float* n2g    = (const float*)d_in[8];
  const float* n2b    = (const float*)d_in[9];
  const float* fc1_w  = (const float*)d_in[10];
  const float* fc1_b  = (const float*)d_in[11];
  const float* fc2_w  = (const float*)d_in[12];
  const float* fc2_b  = (const float*)d_in[13];
  const int*   ridx   = (const int*)d_in[14];
  float* out = (float*)d_out;

  char* ws = (char*)d_ws;
  __bf16* wq   = (__bf16*)(ws);
  __bf16* wp   = (__bf16*)(ws + (1ull << 20));
  __bf16* w1   = (__bf16*)(ws + (2ull << 20));
  __bf16* w2   = (__bf16*)(ws + (4ull << 20));
  __bf16* xwb  = (__bf16*)(ws + (6ull << 20));
  __bf16* hb   = xwb;                          // overlay (xwb dead)
  __bf16* qkvc = (__bf16*)(ws + (90ull << 20));
  __bf16* obuf = (__bf16*)(ws + (146ull << 20));
  __bf16* m1c  = obuf;                         // overlay (obuf dead)

  // weight transpose+convert (fp32 [K][N] -> bf16 [N][K])
  wconv_k<<<dim3(1152 / 32, 384 / 32), 256, 0, stream>>>(qkv_w, wq, 384, 1152);
  wconv_k<<<dim3(384 / 32, 384 / 32), 256, 0, stream>>>(proj_w, wp, 384, 384);
  wconv_k<<<dim3(1536 / 32, 384 / 32), 256, 0, stream>>>(fc1_w, w1, 384, 1536);
  wconv_k<<<dim3(384 / 32, 1536 / 32), 256, 0, stream>>>(fc2_w, w2, 1536, 384);

  // LN1 + shift + window partition -> xwb
  ln1_gather_k<<<Mrows / 4, dim3(64, 4), 0, stream>>>(x, n1g, n1b, xwb);

  // qkv GEMM + attention, 4 chunks of 512 windows
  for (int c = 0; c < 4; ++c) {
    gemm_k<0, 384, 1152><<<dim3(9, CHR / 128), 256, 0, stream>>>(
        xwb + (size_t)c * CHR * Cc, wq, qkv_b, qkvc, nullptr, 0);
    attn_k<<<CHW * Nh, 256, 0, stream>>>(qkvc, rtab, ridx, obuf, c * CHW);
  }

  // proj GEMM + window reverse + residual -> out (= h)
  gemm_k<1, 384, 384><<<dim3(3, Mrows / 128), 256, 0, stream>>>(
      obuf, wp, proj_b, out, x, 0);

  // LN2 -> hb
  ln_apply_k<<<Mrows / 4, dim3(64, 4), 0, stream>>>(out, n2g, n2b, hb);

  // MLP, 4 row-chunks of 25088
  for (int c = 0; c < 4; ++c) {
    gemm_k<2, 384, 1536><<<dim3(12, CHR / 128), 256, 0, stream>>>(
        hb + (size_t)c * CHR * Cc, w1, fc1_b, m1c, nullptr, 0);
    gemm_k<3, 1536, 384><<<dim3(3, CHR / 128), 256, 0, stream>>>(
        m1c, w2, fc2_b, out, nullptr, c * CHR);
  }
}

// Round 7
// 1382.806 us; speedup vs baseline: 1.3371x; 1.3371x over previous
//
#include <hip/hip_runtime.h>
#include <math.h>

typedef float  f32x4  __attribute__((ext_vector_type(4)));
typedef __bf16 bf16x8 __attribute__((ext_vector_type(8)));
typedef __bf16 bf16x4 __attribute__((ext_vector_type(4)));

// Swin block: B=32, H=W=56, C=384, WS=7, SHIFT=3, NH=12, HD=32
constexpr int Cc    = 384;
constexpr int Nh    = 12;
constexpr int Nt    = 49;
constexpr int Mrows = 100352;           // B*H*W
constexpr int CHW   = 512;              // windows per chunk
constexpr int CHR   = CHW * Nt;         // 25088 rows per chunk (= Mrows/4)
constexpr size_t TQ2 = (size_t)CHW * Nh * Nt * 32;  // elems per q/k plane

// async global->LDS, 16B per lane; dest = wave-uniform base + lane*16
__device__ __forceinline__ void gload16(void* lds, const void* g) {
  __builtin_amdgcn_global_load_lds(
      (const __attribute__((address_space(1))) unsigned int*)(uintptr_t)g,
      (__attribute__((address_space(3))) unsigned int*)(uintptr_t)lds,
      16, 0, 0);
}

// ---------------------------------------------------------------------------
// Weight convert: W[K][N] fp32 -> Wt[N][K] bf16 (transposed, GEMM B input)
// ---------------------------------------------------------------------------
__global__ __launch_bounds__(256) void wconv_k(
    const float* __restrict__ W, __bf16* __restrict__ Wt, int K, int N)
{
  __shared__ float T[32][36];
  const int k0 = blockIdx.y * 32, n0 = blockIdx.x * 32;
  const int t = threadIdx.x;
  {
    int r = t >> 3, c = (t & 7) * 4;
    float4 v = *(const float4*)&W[(size_t)(k0 + r) * N + n0 + c];
    T[r][c] = v.x; T[r][c + 1] = v.y; T[r][c + 2] = v.z; T[r][c + 3] = v.w;
  }
  __syncthreads();
  int n = t >> 3, k4 = (t & 7) * 4;
  bf16x4 o;
  o[0] = (__bf16)T[k4 + 0][n];
  o[1] = (__bf16)T[k4 + 1][n];
  o[2] = (__bf16)T[k4 + 2][n];
  o[3] = (__bf16)T[k4 + 3][n];
  *(bf16x4*)&Wt[(size_t)(n0 + n) * K + k0 + k4] = o;
}

// ---------------------------------------------------------------------------
// Relative-position bias, padded to [12][64][64] fp32. Cols m>=49 get -1e30
// so softmax emits exact P=0 there (masks V padding garbage for free).
// ---------------------------------------------------------------------------
__global__ __launch_bounds__(256) void bias_k(
    const float* __restrict__ table, const int* __restrict__ ridx,
    float* __restrict__ biasf)
{
  int i = blockIdx.x * 256 + threadIdx.x;       // < 12*64*64 = 49152
  int h = i >> 12, rem = i & 4095, n = rem >> 6, m = rem & 63;
  biasf[i] = (n < 49 && m < 49) ? table[ridx[n * 49 + m] * 12 + h] : -1e30f;
}

// ---------------------------------------------------------------------------
// LN1 + cyclic shift(-3,-3) + window partition -> xwbc bf16 [CHR][384]
// (rows p0..p0+CHR-1 of the windowed ordering; output chunk-local)
// ---------------------------------------------------------------------------
__global__ __launch_bounds__(256) void ln1_gather_k(
    const float* __restrict__ x, const float* __restrict__ g,
    const float* __restrict__ bt, __bf16* __restrict__ xw, int p0)
{
  int row  = p0 + blockIdx.x * 4 + threadIdx.y;
  int lane = threadIdx.x;
  int w  = row / 49, nn = row - w * 49;
  int b  = w >> 6, wi = (w & 63) >> 3, wj = w & 7;
  int ii = nn / 7, jj = nn - ii * 7;
  int y  = (wi * 7 + ii + 3) % 56;
  int xx = (wj * 7 + jj + 3) % 56;
  const float* xr = x + ((size_t)b * 3136 + y * 56 + xx) * Cc;
  float vals[6], s = 0.f, s2 = 0.f;
#pragma unroll
  for (int t = 0; t < 6; ++t) {
    float v = xr[lane + t * 64];
    vals[t] = v; s += v; s2 += v * v;
  }
#pragma unroll
  for (int off = 32; off > 0; off >>= 1) {
    s  += __shfl_xor(s, off, 64);
    s2 += __shfl_xor(s2, off, 64);
  }
  float mean = s * (1.f / 384.f);
  float var  = s2 * (1.f / 384.f) - mean * mean;
  float rstd = rsqrtf(var + 1e-5f);
  __bf16* orow = xw + (size_t)(row - p0) * Cc;
#pragma unroll
  for (int t = 0; t < 6; ++t) {
    int c = lane + t * 64;
    orow[c] = (__bf16)((vals[t] - mean) * rstd * g[c] + bt[c]);
  }
}

// ---------------------------------------------------------------------------
// LN2 apply: h fp32 [Mrows][384] -> hb bf16
// ---------------------------------------------------------------------------
__global__ __launch_bounds__(256) void ln_apply_k(
    const float* __restrict__ h, const float* __restrict__ g,
    const float* __restrict__ bt, __bf16* __restrict__ o)
{
  int row  = blockIdx.x * 4 + threadIdx.y;
  int lane = threadIdx.x;
  const float* xr = h + (size_t)row * Cc;
  float vals[6], s = 0.f, s2 = 0.f;
#pragma unroll
  for (int t = 0; t < 6; ++t) {
    float v = xr[lane + t * 64];
    vals[t] = v; s += v; s2 += v * v;
  }
#pragma unroll
  for (int off = 32; off > 0; off >>= 1) {
    s  += __shfl_xor(s, off, 64);
    s2 += __shfl_xor(s2, off, 64);
  }
  float mean = s * (1.f / 384.f);
  float var  = s2 * (1.f / 384.f) - mean * mean;
  float rstd = rsqrtf(var + 1e-5f);
  __bf16* orow = o + (size_t)row * Cc;
#pragma unroll
  for (int t = 0; t < 6; ++t) {
    int c = lane + t * 64;
    orow[c] = (__bf16)((vals[t] - mean) * rstd * g[c] + bt[c]);
  }
}

// ---------------------------------------------------------------------------
// bf16 MFMA GEMM: C = A[M,K] @ Bt[N,K]^T (+bias). 128x128 tile, BK=32,
// 4 waves, 4x4 16x16x32 frags/wave, global_load_lds staging (m97 structure).
// MODE 0 qkv : q*scale -> qk plane0; k -> plane1; v transposed+padded -> aux
// MODE 1 proj: out fp32 d_out, window-reverse scatter, + x (e0)
// MODE 2 fc1 : out bf16 (m1c), GELU
// MODE 3 fc2 : out fp32 d_out rows p0+row, +=
// ---------------------------------------------------------------------------
template<int MODE, int K, int NOUT>
__global__ __launch_bounds__(256) void gemm_k(
    const __bf16* __restrict__ A, const __bf16* __restrict__ Bt,
    const float* __restrict__ bias, void* __restrict__ outv,
    const float* __restrict__ e0, void* __restrict__ aux, int p0)
{
  __shared__ __bf16 Alds[128][32];
  __shared__ __bf16 Blds[128][32];
  const int tid  = threadIdx.x;
  const int lane = tid & 63, w = tid >> 6;
  const int m0 = blockIdx.y * 128, n0 = blockIdx.x * 128;
  const int wr = (w >> 1) * 64, wc = (w & 1) * 64;

  f32x4 acc[4][4] = {};

  const int sr = lane >> 2;              // slab row 0..15
  const int sc = (lane & 3) * 8;         // k-elem offset (16B)
  const __bf16* ag = A  + (size_t)(m0 + w * 32 + sr) * K + sc;
  const __bf16* bg = Bt + (size_t)(n0 + w * 32 + sr) * K + sc;
  __bf16* al = &Alds[w * 32][0];
  __bf16* bl = &Blds[w * 32][0];

  const int fr = lane & 15;
  const int fk = (lane >> 4) * 8;

  for (int k0 = 0; k0 < K; k0 += 32) {
    __syncthreads();
    gload16(al,           ag + k0);
    gload16(al + 16 * 32, ag + (size_t)16 * K + k0);
    gload16(bl,           bg + k0);
    gload16(bl + 16 * 32, bg + (size_t)16 * K + k0);
    __syncthreads();

    bf16x8 af[4], bf[4];
#pragma unroll
    for (int mi = 0; mi < 4; ++mi)
      af[mi] = *(const bf16x8*)&Alds[wr + mi * 16 + fr][fk];
#pragma unroll
    for (int ni = 0; ni < 4; ++ni)
      bf[ni] = *(const bf16x8*)&Blds[wc + ni * 16 + fr][fk];
#pragma unroll
    for (int mi = 0; mi < 4; ++mi)
#pragma unroll
      for (int ni = 0; ni < 4; ++ni)
        acc[mi][ni] = __builtin_amdgcn_mfma_f32_16x16x32_bf16(
            af[mi], bf[ni], acc[mi][ni], 0, 0, 0);
  }

  const int col_l = lane & 15;
  const int row_l = (lane >> 4) * 4;
#pragma unroll
  for (int mi = 0; mi < 4; ++mi) {
#pragma unroll
    for (int ni = 0; ni < 4; ++ni) {
#pragma unroll
      for (int r = 0; r < 4; ++r) {
        int row  = m0 + wr + mi * 16 + row_l + r;
        int ccol = n0 + wc + ni * 16 + col_l;
        float val = acc[mi][ni][r] + bias[ccol];
        if (MODE == 0) {
          __bf16* qk = (__bf16*)outv;
          __bf16* vt = (__bf16*)aux;
          int t = ccol / 384, rem = ccol - t * 384;
          int hh = rem >> 5, dd = rem & 31;
          int wl = row / 49, nn = row - wl * 49;
          size_t wh = (size_t)wl * Nh + hh;
          if (t == 0)
            qk[(wh * 49 + nn) * 32 + dd] = (__bf16)(val * 0.17677669529663687f);
          else if (t == 1)
            qk[TQ2 + (wh * 49 + nn) * 32 + dd] = (__bf16)val;
          else
            vt[(wh * 32 + dd) * 64 + nn] = (__bf16)val;   // transposed+padded
        } else if (MODE == 1) {
          float* out = (float*)outv;
          int wg = row / 49, nn = row - wg * 49;
          int b = wg >> 6, wi = (wg & 63) >> 3, wj = wg & 7;
          int ii = nn / 7, jj = nn - ii * 7;
          int y  = (wi * 7 + ii + 3) % 56;
          int xx = (wj * 7 + jj + 3) % 56;
          size_t dest = ((size_t)b * 3136 + y * 56 + xx) * Cc + ccol;
          out[dest] = e0[dest] + val;     // e0 = x (shortcut); h
        } else if (MODE == 2) {
          __bf16* out = (__bf16*)outv;
          float ge = 0.5f * val * (1.0f + erff(val * 0.7071067811865476f));
          out[(size_t)row * NOUT + ccol] = (__bf16)ge;
        } else {
          float* out = (float*)outv;
          size_t idx = (size_t)(p0 + row) * NOUT + ccol;
          out[idx] += val;                // out holds h; final = h + mlp
        }
      }
    }
  }
}

// ---------------------------------------------------------------------------
// MFMA windowed attention: one wave per (window, head), 64x64-padded S.
// QK^T (16 MFMA) -> +bias (padded cols = -1e30) -> wave-parallel softmax
// -> P via LDS [64][72] -> PV (16 MFMA) with pre-transposed V [32][64].
// ---------------------------------------------------------------------------
__global__ __launch_bounds__(256) void attn_mfma_k(
    const __bf16* __restrict__ qk, const __bf16* __restrict__ vt,
    const float* __restrict__ biasf, __bf16* __restrict__ out, int w0)
{
  __shared__ __bf16 P[4][64][72];
  const int tid = threadIdx.x, lane = tid & 63, wv = tid >> 6;
  const int idx = blockIdx.x * 4 + wv;
  const int wl = idx / 12, hh = idx - wl * 12;
  const int fr = lane & 15, fg = lane >> 4;
  const __bf16* qp = qk + (size_t)(wl * Nh + hh) * (49 * 32);
  const __bf16* kp = qp + TQ2;
  const __bf16* vp = vt + (size_t)(wl * Nh + hh) * (32 * 64);

  // ---- S = (q*scale) K^T : rows 49..63 read adjacent data (finite garbage,
  // never stored); cols 49..63 masked by bias = -1e30.
  bf16x8 aq[4], bk[4];
#pragma unroll
  for (int mi = 0; mi < 4; ++mi)
    aq[mi] = *(const bf16x8*)(qp + (mi * 16 + fr) * 32 + fg * 8);
#pragma unroll
  for (int ni = 0; ni < 4; ++ni)
    bk[ni] = *(const bf16x8*)(kp + (ni * 16 + fr) * 32 + fg * 8);
  f32x4 S[4][4] = {};
#pragma unroll
  for (int mi = 0; mi < 4; ++mi)
#pragma unroll
    for (int ni = 0; ni < 4; ++ni)
      S[mi][ni] = __builtin_amdgcn_mfma_f32_16x16x32_bf16(
          aq[mi], bk[ni], S[mi][ni], 0, 0, 0);

  // ---- bias + row softmax (row group = 16 lanes sharing fg; xor low 4 bits)
  const float* bb = biasf + hh * 4096;
#pragma unroll
  for (int mi = 0; mi < 4; ++mi) {
#pragma unroll
    for (int r = 0; r < 4; ++r) {
      int row = mi * 16 + fg * 4 + r;
      float v0 = S[mi][0][r] + bb[row * 64 +  0 + fr];
      float v1 = S[mi][1][r] + bb[row * 64 + 16 + fr];
      float v2 = S[mi][2][r] + bb[row * 64 + 32 + fr];
      float v3 = S[mi][3][r] + bb[row * 64 + 48 + fr];
      float mx = fmaxf(fmaxf(v0, v1), fmaxf(v2, v3));
#pragma unroll
      for (int off = 1; off < 16; off <<= 1)
        mx = fmaxf(mx, __shfl_xor(mx, off, 64));
      v0 = __expf(v0 - mx); v1 = __expf(v1 - mx);
      v2 = __expf(v2 - mx); v3 = __expf(v3 - mx);
      float sum = v0 + v1 + v2 + v3;
#pragma unroll
      for (int off = 1; off < 16; off <<= 1)
        sum += __shfl_xor(sum, off, 64);
      float inv = 1.f / sum;
      P[wv][row][ 0 + fr] = (__bf16)(v0 * inv);
      P[wv][row][16 + fr] = (__bf16)(v1 * inv);
      P[wv][row][32 + fr] = (__bf16)(v2 * inv);
      P[wv][row][48 + fr] = (__bf16)(v3 * inv);
    }
  }

  // ---- O = P V  (contraction over 64 padded cols; cols>=49 have P=0)
  f32x4 O[4][2] = {};
#pragma unroll
  for (int ks = 0; ks < 2; ++ks) {
    bf16x8 bv[2];
#pragma unroll
    for (int ni = 0; ni < 2; ++ni)
      bv[ni] = *(const bf16x8*)(vp + (ni * 16 + fr) * 64 + ks * 32 + fg * 8);
#pragma unroll
    for (int mi = 0; mi < 4; ++mi) {
      bf16x8 pa = *(const bf16x8*)&P[wv][mi * 16 + fr][ks * 32 + fg * 8];
#pragma unroll
      for (int ni = 0; ni < 2; ++ni)
        O[mi][ni] = __builtin_amdgcn_mfma_f32_16x16x32_bf16(
            pa, bv[ni], O[mi][ni], 0, 0, 0);
    }
  }

  const int gw = w0 + wl;
#pragma unroll
  for (int mi = 0; mi < 4; ++mi) {
#pragma unroll
    for (int r = 0; r < 4; ++r) {
      int n = mi * 16 + fg * 4 + r;
      if (n < 49) {
#pragma unroll
        for (int ni = 0; ni < 2; ++ni)
          out[((size_t)gw * 49 + n) * Cc + hh * 32 + ni * 16 + fr] =
              (__bf16)O[mi][ni][r];
      }
    }
  }
}

// ---------------------------------------------------------------------------
// Workspace (peak ~161.5 MiB; 219.5 proven available):
//   @0       wq bf16 [1152][384]
//   @1MiB    wp bf16 [384][384]
//   @2MiB    w1 bf16 [1536][384]
//   @4MiB    w2 bf16 [384][1536]
//   @5.25MiB biasf fp32 [12][64][64] (192KB)
//   @6MiB    xwbc bf16 [CHR][384] (18.4MiB)      } all dead after attn loop;
//   @25MiB   qkc  bf16 [2][CHW*12][49][32] (36.75MiB) } hb overlays @6MiB
//   @62MiB   vtc  bf16 [CHW*12][32][64] (24MiB)  }
//   @88MiB   obuf bf16 [Mrows][384] (73.5MiB) -> reused as m1c after proj
// ---------------------------------------------------------------------------
extern "C" void kernel_launch(void* const* d_in, const int* in_sizes, int n_in,
                              void* d_out, int out_size, void* d_ws, size_t ws_size,
                              hipStream_t stream)
{
  const float* x      = (const float*)d_in[0];
  const float* n1g    = (const float*)d_in[1];
  const float* n1b    = (const float*)d_in[2];
  const float* qkv_w  = (const float*)d_in[3];
  const float* qkv_b  = (const float*)d_in[4];
  const float* proj_w = (const float*)d_in[5];
  const float* proj_b = (const float*)d_in[6];
  const float* rtab   = (const float*)d_in[7];
  const float* n2g    = (const float*)d_in[8];
  const float* n2b    = (const float*)d_in[9];
  const float* fc1_w  = (const float*)d_in[10];
  const float* fc1_b  = (const float*)d_in[11];
  const float* fc2_w  = (const float*)d_in[12];
  const float* fc2_b  = (const float*)d_in[13];
  const int*   ridx   = (const int*)d_in[14];
  float* out = (float*)d_out;

  char* ws = (char*)d_ws;
  __bf16* wq    = (__bf16*)(ws);
  __bf16* wp    = (__bf16*)(ws + (1ull << 20));
  __bf16* w1    = (__bf16*)(ws + (2ull << 20));
  __bf16* w2    = (__bf16*)(ws + (4ull << 20));
  float*  biasf = (float*)(ws + (5ull << 20) + (1ull << 18));
  __bf16* xwbc  = (__bf16*)(ws + (6ull << 20));
  __bf16* qkc   = (__bf16*)(ws + (25ull << 20));
  __bf16* vtc   = (__bf16*)(ws + (62ull << 20));
  __bf16* hb    = (__bf16*)(ws + (6ull << 20));   // overlay after attn phase
  __bf16* obuf  = (__bf16*)(ws + (88ull << 20));
  __bf16* m1c   = obuf;                           // overlay after proj

  // weight transpose+convert; padded bias matrix
  wconv_k<<<dim3(1152 / 32, 384 / 32), 256, 0, stream>>>(qkv_w, wq, 384, 1152);
  wconv_k<<<dim3(384 / 32, 384 / 32), 256, 0, stream>>>(proj_w, wp, 384, 384);
  wconv_k<<<dim3(1536 / 32, 384 / 32), 256, 0, stream>>>(fc1_w, w1, 384, 1536);
  wconv_k<<<dim3(384 / 32, 1536 / 32), 256, 0, stream>>>(fc2_w, w2, 1536, 384);
  bias_k<<<192, 256, 0, stream>>>(rtab, ridx, biasf);

  // LN1+gather -> qkv GEMM -> MFMA attention, 4 chunks of 512 windows
  for (int c = 0; c < 4; ++c) {
    ln1_gather_k<<<CHR / 4, dim3(64, 4), 0, stream>>>(x, n1g, n1b, xwbc, c * CHR);
    gemm_k<0, 384, 1152><<<dim3(9, CHR / 128), 256, 0, stream>>>(
        xwbc, wq, qkv_b, qkc, nullptr, vtc, 0);
    attn_mfma_k<<<CHW * Nh / 4, 256, 0, stream>>>(qkc, vtc, biasf, obuf, c * CHW);
  }

  // proj GEMM + window reverse + residual -> out (= h)
  gemm_k<1, 384, 384><<<dim3(3, Mrows / 128), 256, 0, stream>>>(
      obuf, wp, proj_b, out, x, nullptr, 0);

  // LN2 -> hb
  ln_apply_k<<<Mrows / 4, dim3(64, 4), 0, stream>>>(out, n2g, n2b, hb);

  // MLP, 4 row-chunks of 25088 (hidden chunk overlays obuf)
  for (int c = 0; c < 4; ++c) {
    gemm_k<2, 384, 1536><<<dim3(12, CHR / 128), 256, 0, stream>>>(
        hb + (size_t)c * CHR * Cc, w1, fc1_b, m1c, nullptr, nullptr, 0);
    gemm_k<3, 1536, 384><<<dim3(3, CHR / 128), 256, 0, stream>>>(
        m1c, w2, fc2_b, out, nullptr, nullptr, c * CHR);
  }
}

// Round 9
// 1370.403 us; speedup vs baseline: 1.3492x; 1.0091x over previous
//
#include <hip/hip_runtime.h>
#include <math.h>

typedef float  f32x4  __attribute__((ext_vector_type(4)));
typedef __bf16 bf16x8 __attribute__((ext_vector_type(8)));
typedef __bf16 bf16x4 __attribute__((ext_vector_type(4)));

// Swin block: B=32, H=W=56, C=384, WS=7, SHIFT=3, NH=12, HD=32
constexpr int Cc    = 384;
constexpr int Nh    = 12;
constexpr int Nt    = 49;
constexpr int Mrows = 100352;           // B*H*W
constexpr int CHW   = 512;              // windows per chunk
constexpr int CHR   = CHW * Nt;         // 25088 rows per chunk (= Mrows/4)
constexpr size_t TQ2 = (size_t)CHW * Nh * Nt * 32;  // elems per q/k plane

// async global->LDS, 16B per lane; dest = wave-uniform base + lane*16
__device__ __forceinline__ void gload16(void* lds, const void* g) {
  __builtin_amdgcn_global_load_lds(
      (const __attribute__((address_space(1))) unsigned int*)(uintptr_t)g,
      (__attribute__((address_space(3))) unsigned int*)(uintptr_t)lds,
      16, 0, 0);
}

// ---------------------------------------------------------------------------
// Weight convert: W[K][N] fp32 -> Wt[N][K] bf16 (transposed, GEMM B input)
// ---------------------------------------------------------------------------
__global__ __launch_bounds__(256) void wconv_k(
    const float* __restrict__ W, __bf16* __restrict__ Wt, int K, int N)
{
  __shared__ float T[32][36];
  const int k0 = blockIdx.y * 32, n0 = blockIdx.x * 32;
  const int t = threadIdx.x;
  {
    int r = t >> 3, c = (t & 7) * 4;
    float4 v = *(const float4*)&W[(size_t)(k0 + r) * N + n0 + c];
    T[r][c] = v.x; T[r][c + 1] = v.y; T[r][c + 2] = v.z; T[r][c + 3] = v.w;
  }
  __syncthreads();
  int n = t >> 3, k4 = (t & 7) * 4;
  bf16x4 o;
  o[0] = (__bf16)T[k4 + 0][n];
  o[1] = (__bf16)T[k4 + 1][n];
  o[2] = (__bf16)T[k4 + 2][n];
  o[3] = (__bf16)T[k4 + 3][n];
  *(bf16x4*)&Wt[(size_t)(n0 + n) * K + k0 + k4] = o;
}

// ---------------------------------------------------------------------------
// Relative-position bias, padded to [12][64][64] fp32. Cols m>=49 get -1e30
// so softmax emits exact P=0 there (masks V padding garbage for free).
// ---------------------------------------------------------------------------
__global__ __launch_bounds__(256) void bias_k(
    const float* __restrict__ table, const int* __restrict__ ridx,
    float* __restrict__ biasf)
{
  int i = blockIdx.x * 256 + threadIdx.x;       // < 12*64*64 = 49152
  int h = i >> 12, rem = i & 4095, n = rem >> 6, m = rem & 63;
  biasf[i] = (n < 49 && m < 49) ? table[ridx[n * 49 + m] * 12 + h] : -1e30f;
}

// ---------------------------------------------------------------------------
// LN1 + cyclic shift(-3,-3) + window partition -> xwbc bf16 [CHR][384]
// ---------------------------------------------------------------------------
__global__ __launch_bounds__(256) void ln1_gather_k(
    const float* __restrict__ x, const float* __restrict__ g,
    const float* __restrict__ bt, __bf16* __restrict__ xw, int p0)
{
  int row  = p0 + blockIdx.x * 4 + threadIdx.y;
  int lane = threadIdx.x;
  int w  = row / 49, nn = row - w * 49;
  int b  = w >> 6, wi = (w & 63) >> 3, wj = w & 7;
  int ii = nn / 7, jj = nn - ii * 7;
  int y  = (wi * 7 + ii + 3) % 56;
  int xx = (wj * 7 + jj + 3) % 56;
  const float* xr = x + ((size_t)b * 3136 + y * 56 + xx) * Cc;
  float vals[6], s = 0.f, s2 = 0.f;
#pragma unroll
  for (int t = 0; t < 6; ++t) {
    float v = xr[lane + t * 64];
    vals[t] = v; s += v; s2 += v * v;
  }
#pragma unroll
  for (int off = 32; off > 0; off >>= 1) {
    s  += __shfl_xor(s, off, 64);
    s2 += __shfl_xor(s2, off, 64);
  }
  float mean = s * (1.f / 384.f);
  float var  = s2 * (1.f / 384.f) - mean * mean;
  float rstd = rsqrtf(var + 1e-5f);
  __bf16* orow = xw + (size_t)(row - p0) * Cc;
#pragma unroll
  for (int t = 0; t < 6; ++t) {
    int c = lane + t * 64;
    orow[c] = (__bf16)((vals[t] - mean) * rstd * g[c] + bt[c]);
  }
}

// ---------------------------------------------------------------------------
// LN2 apply: h fp32 [Mrows][384] -> hb bf16
// ---------------------------------------------------------------------------
__global__ __launch_bounds__(256) void ln_apply_k(
    const float* __restrict__ h, const float* __restrict__ g,
    const float* __restrict__ bt, __bf16* __restrict__ o)
{
  int row  = blockIdx.x * 4 + threadIdx.y;
  int lane = threadIdx.x;
  const float* xr = h + (size_t)row * Cc;
  float vals[6], s = 0.f, s2 = 0.f;
#pragma unroll
  for (int t = 0; t < 6; ++t) {
    float v = xr[lane + t * 64];
    vals[t] = v; s += v; s2 += v * v;
  }
#pragma unroll
  for (int off = 32; off > 0; off >>= 1) {
    s  += __shfl_xor(s, off, 64);
    s2 += __shfl_xor(s2, off, 64);
  }
  float mean = s * (1.f / 384.f);
  float var  = s2 * (1.f / 384.f) - mean * mean;
  float rstd = rsqrtf(var + 1e-5f);
  __bf16* orow = o + (size_t)row * Cc;
#pragma unroll
  for (int t = 0; t < 6; ++t) {
    int c = lane + t * 64;
    orow[c] = (__bf16)((vals[t] - mean) * rstd * g[c] + bt[c]);
  }
}

// ---------------------------------------------------------------------------
// bf16 MFMA GEMM: C = A[M,K] @ Bt[N,K]^T (+bias). 128x128 tile, BK=32,
// 4 waves, 4x4 16x16x32 frags/wave, global_load_lds staging (m97 structure).
// Epilogues:
//   MODE 0 qkv : t0/t1 (q*scale, k) -> LDS-transpose -> 16B stores into qk
//                planes; t2 (v) -> scalar transposed scatter into vt.
//   MODE 1 proj: fp32 d_out, window-reverse scatter, + x (e0). scalar.
//   MODE 2 fc1 : tanh-GELU -> LDS-transpose -> 16B stores (bf16 m1c).
//   MODE 3 fc2 : fp32 d_out rows p0+row, +=. scalar.
// ---------------------------------------------------------------------------
template<int MODE, int K, int NOUT>
__global__ __launch_bounds__(256) void gemm_k(
    const __bf16* __restrict__ A, const __bf16* __restrict__ Bt,
    const float* __restrict__ bias, void* __restrict__ outv,
    const float* __restrict__ e0, void* __restrict__ aux, int p0)
{
  __shared__ __bf16 lds[2][128][32];      // [0]=A tile, [1]=B tile (contiguous)
  const int tid  = threadIdx.x;
  const int lane = tid & 63, w = tid >> 6;
  const int m0 = blockIdx.y * 128, n0 = blockIdx.x * 128;
  const int wr = (w >> 1) * 64, wc = (w & 1) * 64;

  f32x4 acc[4][4] = {};

  const int sr = lane >> 2;              // slab row 0..15
  const int sc = (lane & 3) * 8;         // k-elem offset (16B)
  const __bf16* ag = A  + (size_t)(m0 + w * 32 + sr) * K + sc;
  const __bf16* bg = Bt + (size_t)(n0 + w * 32 + sr) * K + sc;
  __bf16* al = &lds[0][w * 32][0];
  __bf16* bl = &lds[1][w * 32][0];

  const int fr = lane & 15;
  const int fk = (lane >> 4) * 8;

  for (int k0 = 0; k0 < K; k0 += 32) {
    __syncthreads();
    gload16(al,           ag + k0);
    gload16(al + 16 * 32, ag + (size_t)16 * K + k0);
    gload16(bl,           bg + k0);
    gload16(bl + 16 * 32, bg + (size_t)16 * K + k0);
    __syncthreads();

    bf16x8 af[4], bf[4];
#pragma unroll
    for (int mi = 0; mi < 4; ++mi)
      af[mi] = *(const bf16x8*)&lds[0][wr + mi * 16 + fr][fk];
#pragma unroll
    for (int ni = 0; ni < 4; ++ni)
      bf[ni] = *(const bf16x8*)&lds[1][wc + ni * 16 + fr][fk];
#pragma unroll
    for (int mi = 0; mi < 4; ++mi)
#pragma unroll
      for (int ni = 0; ni < 4; ++ni)
        acc[mi][ni] = __builtin_amdgcn_mfma_f32_16x16x32_bf16(
            af[mi], bf[ni], acc[mi][ni], 0, 0, 0);
  }

  const int col_l = lane & 15;
  const int row_l = (lane >> 4) * 4;     // fg*4

  if (MODE == 1 || MODE == 3) {
    // fp32 outputs: scalar path (4B x 16-lane segments already coalesced)
#pragma unroll
    for (int mi = 0; mi < 4; ++mi) {
#pragma unroll
      for (int ni = 0; ni < 4; ++ni) {
#pragma unroll
        for (int r = 0; r < 4; ++r) {
          int row  = m0 + wr + mi * 16 + row_l + r;
          int ccol = n0 + wc + ni * 16 + col_l;
          float val = acc[mi][ni][r] + bias[ccol];
          if (MODE == 1) {
            float* out = (float*)outv;
            int wg = row / 49, nn = row - wg * 49;
            int b = wg >> 6, wi = (wg & 63) >> 3, wj = wg & 7;
            int ii = nn / 7, jj = nn - ii * 7;
            int y  = (wi * 7 + ii + 3) % 56;
            int xx = (wj * 7 + jj + 3) % 56;
            size_t dest = ((size_t)b * 3136 + y * 56 + xx) * Cc + ccol;
            out[dest] = e0[dest] + val;     // e0 = x (shortcut); h
          } else {
            float* out = (float*)outv;
            size_t idx = (size_t)(p0 + row) * NOUT + ccol;
            out[idx] += val;                // out holds h; final = h + mlp
          }
        }
      }
    }
  } else {
    // bf16 outputs. All waves done with K-loop LDS reads before repurposing.
    __syncthreads();
    const int q0 = n0 + wc;               // quadrant col base (64-aligned)
    if (MODE == 0 && q0 >= 768) {
      // V plane: vt[(wh*32+dd)*64+nn], contiguous along nn -> scalar scatter
      __bf16* vt = (__bf16*)aux;
#pragma unroll
      for (int mi = 0; mi < 4; ++mi) {
#pragma unroll
        for (int ni = 0; ni < 4; ++ni) {
          int ccol = q0 + ni * 16 + col_l;
          int rem = ccol - 768, hh = rem >> 5, dd = rem & 31;
          float bv = bias[ccol];
#pragma unroll
          for (int r = 0; r < 4; ++r) {
            int row = m0 + wr + mi * 16 + row_l + r;
            int wl = row / 49, nn = row - wl * 49;
            vt[((size_t)wl * Nh + hh) * 2048 + dd * 64 + nn] =
                (__bf16)(acc[mi][ni][r] + bv);
          }
        }
      }
    } else {
      // LDS-transpose: per-wave private slab [16][72] bf16 (144B rows,
      // 16B-aligned, bank-rotating). 2048-elem slab region per wave.
      __bf16* slab = &lds[0][0][0] + (size_t)w * 2048;
      const float qsc = (MODE == 0 && q0 < 384) ? 0.17677669529663687f : 1.f;
#pragma unroll
      for (int mi = 0; mi < 4; ++mi) {
        // scatter acc -> slab (transpose in): 16 ds_write_b16
#pragma unroll
        for (int ni = 0; ni < 4; ++ni) {
          float bv = bias[q0 + ni * 16 + col_l];
#pragma unroll
          for (int r = 0; r < 4; ++r) {
            float val = acc[mi][ni][r] + bv;
            if (MODE == 2) {
              // gelu(x) = x / (1 + e^(-2u)), u = x*(c1 + c2*x^2)  [tanh form]
              float u = val * (0.7978845608028654f + 0.0356774081f * val * val);
              val = val / (1.f + __expf(-2.f * u));
            } else {
              val *= qsc;
            }
            slab[(row_l + r) * 72 + ni * 16 + col_l] = (__bf16)val;
          }
        }
        asm volatile("s_waitcnt lgkmcnt(0)" ::: "memory");
        // gather slab rows -> vectorized 16B global stores (2 passes x 8 rows)
#pragma unroll
        for (int p = 0; p < 2; ++p) {
          int lrow = p * 8 + (lane >> 3);
          int c0 = (lane & 7) * 8;
          bf16x8 vv = *(const bf16x8*)&slab[lrow * 72 + c0];
          int grow = m0 + wr + mi * 16 + lrow;
          if (MODE == 2) {
            *(bf16x8*)((__bf16*)outv + (size_t)grow * NOUT + q0 + c0) = vv;
          } else {
            int t = (q0 >= 384) ? 1 : 0;
            int rem = q0 - t * 384 + c0;
            int hh = rem >> 5, dd0 = rem & 31;
            int wl = grow / 49, nn = grow - wl * 49;
            __bf16* qk = (__bf16*)outv + (size_t)t * TQ2;
            *(bf16x8*)&qk[(((size_t)wl * Nh + hh) * 49 + nn) * 32 + dd0] = vv;
          }
        }
        asm volatile("s_waitcnt lgkmcnt(0)" ::: "memory");  // reads done
      }
    }
  }
}

// ---------------------------------------------------------------------------
// MFMA windowed attention: one wave per (window, head), 64x64-padded S.
// QK^T (16 MFMA) -> +bias (padded cols = -1e30) -> wave-parallel softmax
// -> P via LDS [64][72] -> PV (16 MFMA) with pre-transposed V [32][64].
// ---------------------------------------------------------------------------
__global__ __launch_bounds__(256) void attn_mfma_k(
    const __bf16* __restrict__ qk, const __bf16* __restrict__ vt,
    const float* __restrict__ biasf, __bf16* __restrict__ out, int w0)
{
  __shared__ __bf16 P[4][64][72];
  const int tid = threadIdx.x, lane = tid & 63, wv = tid >> 6;
  const int idx = blockIdx.x * 4 + wv;
  const int wl = idx / 12, hh = idx - wl * 12;
  const int fr = lane & 15, fg = lane >> 4;
  const __bf16* qp = qk + (size_t)(wl * Nh + hh) * (49 * 32);
  const __bf16* kp = qp + TQ2;
  const __bf16* vp = vt + (size_t)(wl * Nh + hh) * (32 * 64);

  bf16x8 aq[4], bk[4];
#pragma unroll
  for (int mi = 0; mi < 4; ++mi)
    aq[mi] = *(const bf16x8*)(qp + (mi * 16 + fr) * 32 + fg * 8);
#pragma unroll
  for (int ni = 0; ni < 4; ++ni)
    bk[ni] = *(const bf16x8*)(kp + (ni * 16 + fr) * 32 + fg * 8);
  f32x4 S[4][4] = {};
#pragma unroll
  for (int mi = 0; mi < 4; ++mi)
#pragma unroll
    for (int ni = 0; ni < 4; ++ni)
      S[mi][ni] = __builtin_amdgcn_mfma_f32_16x16x32_bf16(
          aq[mi], bk[ni], S[mi][ni], 0, 0, 0);

  const float* bb = biasf + hh * 4096;
#pragma unroll
  for (int mi = 0; mi < 4; ++mi) {
#pragma unroll
    for (int r = 0; r < 4; ++r) {
      int row = mi * 16 + fg * 4 + r;
      float v0 = S[mi][0][r] + bb[row * 64 +  0 + fr];
      float v1 = S[mi][1][r] + bb[row * 64 + 16 + fr];
      float v2 = S[mi][2][r] + bb[row * 64 + 32 + fr];
      float v3 = S[mi][3][r] + bb[row * 64 + 48 + fr];
      float mx = fmaxf(fmaxf(v0, v1), fmaxf(v2, v3));
#pragma unroll
      for (int off = 1; off < 16; off <<= 1)
        mx = fmaxf(mx, __shfl_xor(mx, off, 64));
      v0 = __expf(v0 - mx); v1 = __expf(v1 - mx);
      v2 = __expf(v2 - mx); v3 = __expf(v3 - mx);
      float sum = v0 + v1 + v2 + v3;
#pragma unroll
      for (int off = 1; off < 16; off <<= 1)
        sum += __shfl_xor(sum, off, 64);
      float inv = 1.f / sum;
      P[wv][row][ 0 + fr] = (__bf16)(v0 * inv);
      P[wv][row][16 + fr] = (__bf16)(v1 * inv);
      P[wv][row][32 + fr] = (__bf16)(v2 * inv);
      P[wv][row][48 + fr] = (__bf16)(v3 * inv);
    }
  }

  f32x4 O[4][2] = {};
#pragma unroll
  for (int ks = 0; ks < 2; ++ks) {
    bf16x8 bv[2];
#pragma unroll
    for (int ni = 0; ni < 2; ++ni)
      bv[ni] = *(const bf16x8*)(vp + (ni * 16 + fr) * 64 + ks * 32 + fg * 8);
#pragma unroll
    for (int mi = 0; mi < 4; ++mi) {
      bf16x8 pa = *(const bf16x8*)&P[wv][mi * 16 + fr][ks * 32 + fg * 8];
#pragma unroll
      for (int ni = 0; ni < 2; ++ni)
        O[mi][ni] = __builtin_amdgcn_mfma_f32_16x16x32_bf16(
            pa, bv[ni], O[mi][ni], 0, 0, 0);
    }
  }

  const int gw = w0 + wl;
#pragma unroll
  for (int mi = 0; mi < 4; ++mi) {
#pragma unroll
    for (int r = 0; r < 4; ++r) {
      int n = mi * 16 + fg * 4 + r;
      if (n < 49) {
#pragma unroll
        for (int ni = 0; ni < 2; ++ni)
          out[((size_t)gw * 49 + n) * Cc + hh * 32 + ni * 16 + fr] =
              (__bf16)O[mi][ni][r];
      }
    }
  }
}

// ---------------------------------------------------------------------------
// Workspace (peak ~161.5 MiB; 219.5 proven available):
//   @0       wq bf16 [1152][384]
//   @1MiB    wp bf16 [384][384]
//   @2MiB    w1 bf16 [1536][384]
//   @4MiB    w2 bf16 [384][1536]
//   @5.25MiB biasf fp32 [12][64][64] (192KB)
//   @6MiB    xwbc bf16 [CHR][384] (18.4MiB)      } all dead after attn loop;
//   @25MiB   qkc  bf16 [2][CHW*12][49][32] (36.75MiB) } hb overlays @6MiB
//   @62MiB   vtc  bf16 [CHW*12][32][64] (24MiB)  }
//   @88MiB   obuf bf16 [Mrows][384] (73.5MiB) -> reused as m1c after proj
// ---------------------------------------------------------------------------
extern "C" void kernel_launch(void* const* d_in, const int* in_sizes, int n_in,
                              void* d_out, int out_size, void* d_ws, size_t ws_size,
                              hipStream_t stream)
{
  const float* x      = (const float*)d_in[0];
  const float* n1g    = (const float*)d_in[1];
  const float* n1b    = (const float*)d_in[2];
  const float* qkv_w  = (const float*)d_in[3];
  const float* qkv_b  = (const float*)d_in[4];
  const float* proj_w = (const float*)d_in[5];
  const float* proj_b = (const float*)d_in[6];
  const float* rtab   = (const float*)d_in[7];
  const float* n2g    = (const float*)d_in[8];
  const float* n2b    = (const float*)d_in[9];
  const float* fc1_w  = (const float*)d_in[10];
  const float* fc1_b  = (const float*)d_in[11];
  const float* fc2_w  = (const float*)d_in[12];
  const float* fc2_b  = (const float*)d_in[13];
  const int*   ridx   = (const int*)d_in[14];
  float* out = (float*)d_out;

  char* ws = (char*)d_ws;
  __bf16* wq    = (__bf16*)(ws);
  __bf16* wp    = (__bf16*)(ws + (1ull << 20));
  __bf16* w1    = (__bf16*)(ws + (2ull << 20));
  __bf16* w2    = (__bf16*)(ws + (4ull << 20));
  float*  biasf = (float*)(ws + (5ull << 20) + (1ull << 18));
  __bf16* xwbc  = (__bf16*)(ws + (6ull << 20));
  __bf16* qkc   = (__bf16*)(ws + (25ull << 20));
  __bf16* vtc   = (__bf16*)(ws + (62ull << 20));
  __bf16* hb    = (__bf16*)(ws + (6ull << 20));   // overlay after attn phase
  __bf16* obuf  = (__bf16*)(ws + (88ull << 20));
  __bf16* m1c   = obuf;                           // overlay after proj

  // weight transpose+convert; padded bias matrix
  wconv_k<<<dim3(1152 / 32, 384 / 32), 256, 0, stream>>>(qkv_w, wq, 384, 1152);
  wconv_k<<<dim3(384 / 32, 384 / 32), 256, 0, stream>>>(proj_w, wp, 384, 384);
  wconv_k<<<dim3(1536 / 32, 384 / 32), 256, 0, stream>>>(fc1_w, w1, 384, 1536);
  wconv_k<<<dim3(384 / 32, 1536 / 32), 256, 0, stream>>>(fc2_w, w2, 1536, 384);
  bias_k<<<192, 256, 0, stream>>>(rtab, ridx, biasf);

  // LN1+gather -> qkv GEMM -> MFMA attention, 4 chunks of 512 windows
  for (int c = 0; c < 4; ++c) {
    ln1_gather_k<<<CHR / 4, dim3(64, 4), 0, stream>>>(x, n1g, n1b, xwbc, c * CHR);
    gemm_k<0, 384, 1152><<<dim3(9, CHR / 128), 256, 0, stream>>>(
        xwbc, wq, qkv_b, qkc, nullptr, vtc, 0);
    attn_mfma_k<<<CHW * Nh / 4, 256, 0, stream>>>(qkc, vtc, biasf, obuf, c * CHW);
  }

  // proj GEMM + window reverse + residual -> out (= h)
  gemm_k<1, 384, 384><<<dim3(3, Mrows / 128), 256, 0, stream>>>(
      obuf, wp, proj_b, out, x, nullptr, 0);

  // LN2 -> hb
  ln_apply_k<<<Mrows / 4, dim3(64, 4), 0, stream>>>(out, n2g, n2b, hb);

  // MLP, 4 row-chunks of 25088 (hidden chunk overlays obuf)
  for (int c = 0; c < 4; ++c) {
    gemm_k<2, 384, 1536><<<dim3(12, CHR / 128), 256, 0, stream>>>(
        hb + (size_t)c * CHR * Cc, w1, fc1_b, m1c, nullptr, nullptr, 0);
    gemm_k<3, 1536, 384><<<dim3(3, CHR / 128), 256, 0, stream>>>(
        m1c, w2, fc2_b, out, nullptr, nullptr, c * CHR);
  }
}